// Round 5
// baseline (625.133 us; speedup 1.0000x reference)
//
#include <hip/hip_runtime.h>
#include <hip/hip_bf16.h>
#include <stdint.h>

#define NP 409600
#define HG 640
#define WG 640
#define HW (HG*WG)
// spatial tiles: 16x16 cells, ~50% density => ~128 points/tile = one conv block
#define TPB  40          // tiles per axis (640/16)
#define NTILE 3200       // 2 * 40 * 40

typedef __bf16 bf16x8 __attribute__((ext_vector_type(8)));
typedef float f32x4 __attribute__((ext_vector_type(4)));

// ---------------- prep kernels ----------------

// counting sort by spatial tile: hist -> exclusive scan -> scatter order
__global__ void hist_kernel(const int* __restrict__ coords, int* __restrict__ hist) {
    int i = blockIdx.x * 256 + threadIdx.x;
    int b = coords[3*i], y = coords[3*i+1], x = coords[3*i+2];
    atomicAdd(&hist[b*(TPB*TPB) + (y>>4)*TPB + (x>>4)], 1);
}

__global__ void scan_kernel(int* __restrict__ hist) {   // 1 block, 256 threads, 13 vals each
    __shared__ int part[256];
    int t = threadIdx.x;
    int loc[13];
    int s = 0;
    #pragma unroll
    for (int k = 0; k < 13; ++k) {
        int idx = t*13 + k;
        int v = (idx < NTILE) ? hist[idx] : 0;
        loc[k] = s; s += v;
    }
    part[t] = s;
    __syncthreads();
    for (int off = 1; off < 256; off <<= 1) {   // Hillis-Steele inclusive scan
        int v = (t >= off) ? part[t - off] : 0;
        __syncthreads();
        part[t] += v;
        __syncthreads();
    }
    int pre = (t > 0) ? part[t-1] : 0;
    #pragma unroll
    for (int k = 0; k < 13; ++k) {
        int idx = t*13 + k;
        if (idx < NTILE) hist[idx] = pre + loc[k];
    }
}

// ord[pos]=orig id; lsort[pos]=packed coord; grid[lin]=sorted pos; inv[i]=pos (coalesced)
__global__ void ord_kernel(const int* __restrict__ coords, int* __restrict__ offs,
                           int* __restrict__ ord, int* __restrict__ lsort,
                           int* __restrict__ grid, int* __restrict__ inv) {
    int i = blockIdx.x * 256 + threadIdx.x;
    int b = coords[3*i], y = coords[3*i+1], x = coords[3*i+2];
    int tile = b*(TPB*TPB) + (y>>4)*TPB + (x>>4);
    int pos = atomicAdd(&offs[tile], 1);
    int lin = b*HW + y*WG + x;
    ord[pos]   = i;
    lsort[pos] = lin;
    grid[lin]  = pos;
    inv[i]     = pos;
}

// permute + cast, COALESCED READ / scattered write: fpermb[inv[i]] = bf16(features[i])
__global__ void perm_cast_kernel(const float* __restrict__ f, const int* __restrict__ inv,
                                 __hip_bfloat16* __restrict__ fpermb) {
    int t = blockIdx.x * 256 + threadIdx.x;       // grid = 12800 blocks
    int i = t >> 3, part = t & 7;                 // i sequential -> coalesced reads
    int j = inv[i];
    const float4* p = (const float4*)(f + (long)i*64 + part*8);
    float4 a = p[0], b = p[1];
    union { uint4 q; __hip_bfloat16 h[8]; } u;
    u.h[0] = __float2bfloat16(a.x); u.h[1] = __float2bfloat16(a.y);
    u.h[2] = __float2bfloat16(a.z); u.h[3] = __float2bfloat16(a.w);
    u.h[4] = __float2bfloat16(b.x); u.h[5] = __float2bfloat16(b.y);
    u.h[6] = __float2bfloat16(b.z); u.h[7] = __float2bfloat16(b.w);
    *(uint4*)(fpermb + (long)j*64 + part*8) = u.q;
}

// neighbor table over SORTED order j; center tap (tt==4) omitted (always self).
// values are SORTED positions (index fpermb / y1 directly)
__global__ void nbr_kernel(const int* __restrict__ lsort, const int* __restrict__ grid,
                           int* __restrict__ nbrp) {
    int j = blockIdx.x * 256 + threadIdx.x;
    int lin = lsort[j];
    int b = lin / HW;
    int rem = lin - b*HW;
    int y = rem / WG;
    int x = rem - y*WG;
    int baseg = b*HW;
    #pragma unroll
    for (int tt = 0; tt < 9; ++tt) {
        if (tt == 4) continue;
        int ti = tt < 4 ? tt : tt - 1;
        int ny = y + tt/3 - 1, nx = x + tt%3 - 1;
        int g = -1;
        if (ny >= 0 && ny < HG && nx >= 0 && nx < WG)
            g = grid[baseg + ny*WG + nx];
        nbrp[ti*NP + j] = g;
    }
}

// weights pre-cast to bf16 in PER-LANE FRAGMENT order:
// flat index o = (((t*2+ks)*4 + c)*64 + lane)*8 + e
// holds w[t][k = ks*32 + (lane>>4)*8 + e][n = c*16 + (lane&15)]
// -> a wave's B-fragment load is ONE contiguous 1KB read (no LDS staging needed).
__global__ void cast_w_kernel(const float* __restrict__ w1, const float* __restrict__ w2,
                              const float* __restrict__ wd,
                              __hip_bfloat16* __restrict__ wc1, __hip_bfloat16* __restrict__ wc2) {
    int i = blockIdx.x * 256 + threadIdx.x;   // grid = 77824 threads exactly
    if (i < 9*4096) {
        int o = i;
        int e = o & 7, l = (o >> 3) & 63, c = (o >> 9) & 3, ks = (o >> 11) & 1, t = o >> 12;
        int n = c*16 + (l & 15), k = ks*32 + (l >> 4)*8 + e;
        wc1[o] = __float2bfloat16(w1[t*4096 + k*64 + n]);
    }
    int j = i - 9*4096;
    if (j >= 0 && j < 10*4096) {
        int o = j;
        int e = o & 7, l = (o >> 3) & 63, c = (o >> 9) & 3, ks = (o >> 11) & 1, t = o >> 12;
        int n = c*16 + (l & 15), k = ks*32 + (l >> 4)*8 + e;
        float v = (t < 9) ? w2[t*4096 + k*64 + n] : wd[k*64 + n];
        wc2[o] = __float2bfloat16(v);
    }
}

// ---------------- gather-GEMM conv kernel ----------------
// 128 sorted rows x 64 cols per block, 4 waves. A staged in DOUBLE-BUFFERED LDS
// (reg-prefetch of next tap before the single per-tap barrier); B read directly
// from global in fragment order (L2-resident, coalesced 1KB/wave-load).
// LDS ops per lane per tap: 4 writes + 4 reads (was 6+12 with B in LDS).
// FINAL: tap 9 = identity(fpermb, contiguous) @ wd into accR initialized at the
// tail only (reference applies relu(conv2+b2) BEFORE adding the residual).

#define LDA 72

template<bool FINAL>
__launch_bounds__(256)
__global__ void conv_kernel(const __hip_bfloat16* __restrict__ src,    // sorted-order gather source
                            const __hip_bfloat16* __restrict__ idsrc,  // identity source (FINAL)
                            const int* __restrict__ nbrp,              // [8][NP] sorted positions
                            const int* __restrict__ ord,               // sorted pos -> orig id
                            const __hip_bfloat16* __restrict__ wT,     // fragment-ordered weights
                            const float* __restrict__ bias,
                            __hip_bfloat16* __restrict__ out_bf,       // sorted order (conv1)
                            float* __restrict__ out_f) {               // original order (conv2)
    __shared__ __align__(16) __hip_bfloat16 As[2][128 * LDA];

    const int tid = threadIdx.x;
    // XCD-aware swizzle: 3200 blocks, 8 XCDs, 400 contiguous spatial tiles per XCD
    const int sbid = (blockIdx.x & 7) * 400 + (blockIdx.x >> 3);
    const int base = sbid * 128;
    const int wave = tid >> 6, lane = tid & 63;
    const int mrow = lane & 15, kq = lane >> 4;
    const int srow = tid >> 1, shalf = tid & 1;   // staging: 2 threads per row

    const bf16x8* wfrag = (const bf16x8*)wT;      // 16B per lane-fragment

    f32x4 acc[2][4];
    f32x4 accR[2][4];   // FINAL only; first written at tap 9 (short live range)
    #pragma unroll
    for (int i = 0; i < 2; ++i)
        #pragma unroll
        for (int j = 0; j < 4; ++j)
            acc[i][j] = (f32x4){0.f, 0.f, 0.f, 0.f};

    const int NT = FINAL ? 10 : 9;

    auto gpos = [&](int t) -> int {
        if (t == 4) return base + srow;              // center tap = self
        if (FINAL && t == 9) return base + srow;     // identity tap rows
        int ti = t < 4 ? t : t - 1;
        return nbrp[ti*NP + base + srow];
    };

    // staging regs (held across one tap's MFMAs: 16 VGPRs)
    uint4 v0, v1, v2, v3;
    auto loadA = [&](int t, int g) {
        const __hip_bfloat16* sp = (FINAL && t == 9) ? idsrc : src;
        if (g >= 0) {
            const uint4* p = (const uint4*)(sp + (long)g*64 + shalf*32);
            v0 = p[0]; v1 = p[1]; v2 = p[2]; v3 = p[3];
        } else {
            v0 = v1 = v2 = v3 = make_uint4(0u, 0u, 0u, 0u);
        }
    };
    auto writeA = [&](int bsel) {
        uint4* dst = (uint4*)(As[bsel] + srow*LDA + shalf*32);
        dst[0] = v0; dst[1] = v1; dst[2] = v2; dst[3] = v3;
    };

    auto mfma_tap = [&](f32x4 (&ac)[2][4], int t, int cur) {
        #pragma unroll
        for (int ks = 0; ks < 2; ++ks) {
            int kb = ks*32 + kq*8;
            bf16x8 a0 = *(const bf16x8*)(&As[cur][(wave*32      + mrow)*LDA + kb]);
            bf16x8 a1 = *(const bf16x8*)(&As[cur][(wave*32 + 16 + mrow)*LDA + kb]);
            int fb = ((t*2 + ks)*4)*64 + lane;
            bf16x8 b0 = wfrag[fb];
            bf16x8 b1 = wfrag[fb + 64];
            bf16x8 b2 = wfrag[fb + 128];
            bf16x8 b3 = wfrag[fb + 192];
            ac[0][0] = __builtin_amdgcn_mfma_f32_16x16x32_bf16(a0, b0, ac[0][0], 0, 0, 0);
            ac[0][1] = __builtin_amdgcn_mfma_f32_16x16x32_bf16(a0, b1, ac[0][1], 0, 0, 0);
            ac[0][2] = __builtin_amdgcn_mfma_f32_16x16x32_bf16(a0, b2, ac[0][2], 0, 0, 0);
            ac[0][3] = __builtin_amdgcn_mfma_f32_16x16x32_bf16(a0, b3, ac[0][3], 0, 0, 0);
            ac[1][0] = __builtin_amdgcn_mfma_f32_16x16x32_bf16(a1, b0, ac[1][0], 0, 0, 0);
            ac[1][1] = __builtin_amdgcn_mfma_f32_16x16x32_bf16(a1, b1, ac[1][1], 0, 0, 0);
            ac[1][2] = __builtin_amdgcn_mfma_f32_16x16x32_bf16(a1, b2, ac[1][2], 0, 0, 0);
            ac[1][3] = __builtin_amdgcn_mfma_f32_16x16x32_bf16(a1, b3, ac[1][3], 0, 0, 0);
        }
    };

    // prologue: stage tap 0, prefetch tap-1 index
    int g = gpos(0);
    loadA(0, g);
    writeA(0);
    g = gpos(1);

    #pragma unroll
    for (int t = 0; t < NT; ++t) {
        // prefetch next tap's rows into regs BEFORE the barrier (latency overlaps)
        if (t + 1 < NT) {
            loadA(t + 1, g);
            if (t + 2 < NT) g = gpos(t + 2);
        }
        __syncthreads();   // single barrier/tap: As[t&1] staged; As[(t+1)&1] readers (tap t-1) done
        if (FINAL && t == NT - 1) {
            #pragma unroll
            for (int i = 0; i < 2; ++i)
                #pragma unroll
                for (int j = 0; j < 4; ++j)
                    accR[i][j] = (f32x4){0.f, 0.f, 0.f, 0.f};
            mfma_tap(accR, t, t & 1);
        } else {
            mfma_tap(acc, t, t & 1);
        }
        if (t + 1 < NT) writeA((t + 1) & 1);
    }

    // ---- epilogue ----
    const int col = mrow, quad = kq;
    #pragma unroll
    for (int cb = 0; cb < 4; ++cb) {
        float bv = bias[cb*16 + col];
        #pragma unroll
        for (int mb = 0; mb < 2; ++mb) {
            #pragma unroll
            for (int r = 0; r < 4; ++r) {
                float v = acc[mb][cb][r] + bv;
                v = v > 0.f ? v : 0.f;
                int srt = base + wave*32 + mb*16 + quad*4 + r;   // sorted row
                int c   = cb*16 + col;
                if (FINAL) {
                    v += accR[mb][cb][r];      // residual added AFTER inner relu
                    v = v > 0.f ? v : 0.f;
                    long row = ord[srt];       // scatter to original order
                    out_f[row*64 + c] = v;
                } else {
                    out_bf[(long)srt*64 + c] = __float2bfloat16(v);   // stay sorted
                }
            }
        }
    }
}

// ---------------- launch ----------------

extern "C" void kernel_launch(void* const* d_in, const int* in_sizes, int n_in,
                              void* d_out, int out_size, void* d_ws, size_t ws_size,
                              hipStream_t stream) {
    const float* features = (const float*)d_in[0];
    const int*   coords   = (const int*)d_in[1];
    const float* w1 = (const float*)d_in[2];
    const float* b1 = (const float*)d_in[3];
    const float* w2 = (const float*)d_in[4];
    const float* b2 = (const float*)d_in[5];
    const float* wd = (const float*)d_in[6];
    float* out = (float*)d_out;

    char* ws = (char*)d_ws;
    int*            grid   = (int*)ws;                           //  3,276,800 B
    int*            nbrp   = (int*)(ws + 3276800);               // 13,107,200 B (8 taps)
    int*            ord    = (int*)(ws + 16384000);              //  1,638,400 B
    __hip_bfloat16* fpermb = (__hip_bfloat16*)(ws + 18022400);   // 52,428,800 B
    __hip_bfloat16* y1     = (__hip_bfloat16*)(ws + 70451200);   // 52,428,800 B
    __hip_bfloat16* wc1    = (__hip_bfloat16*)(ws + 122880000);  //     73,728 B
    __hip_bfloat16* wc2    = (__hip_bfloat16*)(ws + 122953728);  //     81,920 B
    // total 123,035,648 B
    // lsort + hist + inv live in y1's region (dead before conv1 writes y1)
    int* lsort = (int*)(ws + 70451200);                          //  1,638,400 B
    int* hist  = (int*)(ws + 70451200 + 1638400);                //     12,800 B
    int* inv   = (int*)(ws + 70451200 + 1651200);                //  1,638,400 B

    hipMemsetAsync(grid, 0xFF, (size_t)HW * 2 * sizeof(int), stream);   // grid = -1
    hipMemsetAsync(hist, 0x00, (size_t)NTILE * sizeof(int), stream);

    hist_kernel     <<<1600,  256, 0, stream>>>(coords, hist);
    scan_kernel     <<<1,     256, 0, stream>>>(hist);
    ord_kernel      <<<1600,  256, 0, stream>>>(coords, hist, ord, lsort, grid, inv);
    cast_w_kernel   <<<304,   256, 0, stream>>>(w1, w2, wd, wc1, wc2);
    nbr_kernel      <<<1600,  256, 0, stream>>>(lsort, grid, nbrp);
    perm_cast_kernel<<<12800, 256, 0, stream>>>(features, inv, fpermb);

    conv_kernel<false><<<3200, 256, 0, stream>>>(fpermb, nullptr, nbrp, ord, wc1, b1, y1, nullptr);
    conv_kernel<true ><<<3200, 256, 0, stream>>>(y1, fpermb, nbrp, ord, wc2, b2, nullptr, out);
}

// Round 6
// 419.097 us; speedup vs baseline: 1.4916x; 1.4916x over previous
//
#include <hip/hip_runtime.h>
#include <hip/hip_bf16.h>
#include <stdint.h>

#define NP 409600
#define HG 640
#define WG 640
#define HW (HG*WG)
// spatial tiles: 16x16 cells, ~50% density => ~128 points/tile = one conv block
#define TPB  40          // tiles per axis (640/16)
#define NTILE 3200       // 2 * 40 * 40

typedef __bf16 bf16x8 __attribute__((ext_vector_type(8)));
typedef float f32x4 __attribute__((ext_vector_type(4)));

// ---------------- prep kernels ----------------

// counting sort by spatial tile: hist -> exclusive scan -> scatter order.
// Also clears grid to -1 (ord_kernel writes it afterwards) -- saves a memset dispatch.
__global__ void hist_kernel(const int* __restrict__ coords, int* __restrict__ hist,
                            int* __restrict__ grid) {
    int i = blockIdx.x * 256 + threadIdx.x;
    *(int2*)(grid + 2*i) = make_int2(-1, -1);   // 409600 threads x 2 = 819200 cells
    int b = coords[3*i], y = coords[3*i+1], x = coords[3*i+2];
    atomicAdd(&hist[b*(TPB*TPB) + (y>>4)*TPB + (x>>4)], 1);
}

__global__ void scan_kernel(int* __restrict__ hist) {   // 1 block, 256 threads, 13 vals each
    __shared__ int part[256];
    int t = threadIdx.x;
    int loc[13];
    int s = 0;
    #pragma unroll
    for (int k = 0; k < 13; ++k) {
        int idx = t*13 + k;
        int v = (idx < NTILE) ? hist[idx] : 0;
        loc[k] = s; s += v;
    }
    part[t] = s;
    __syncthreads();
    for (int off = 1; off < 256; off <<= 1) {   // Hillis-Steele inclusive scan
        int v = (t >= off) ? part[t - off] : 0;
        __syncthreads();
        part[t] += v;
        __syncthreads();
    }
    int pre = (t > 0) ? part[t-1] : 0;
    #pragma unroll
    for (int k = 0; k < 13; ++k) {
        int idx = t*13 + k;
        if (idx < NTILE) hist[idx] = pre + loc[k];
    }
}

// ord[pos]=orig id; lsort[pos]=packed coord; grid[lin]=sorted pos; inv[i]=pos (coalesced)
__global__ void ord_kernel(const int* __restrict__ coords, int* __restrict__ offs,
                           int* __restrict__ ord, int* __restrict__ lsort,
                           int* __restrict__ grid, int* __restrict__ inv) {
    int i = blockIdx.x * 256 + threadIdx.x;
    int b = coords[3*i], y = coords[3*i+1], x = coords[3*i+2];
    int tile = b*(TPB*TPB) + (y>>4)*TPB + (x>>4);
    int pos = atomicAdd(&offs[tile], 1);
    int lin = b*HW + y*WG + x;
    ord[pos]   = i;
    lsort[pos] = lin;
    grid[lin]  = pos;
    inv[i]     = pos;
}

// permute + cast, COALESCED READ / scattered write: fpermb[inv[i]] = bf16(features[i])
__global__ void perm_cast_kernel(const float* __restrict__ f, const int* __restrict__ inv,
                                 __hip_bfloat16* __restrict__ fpermb) {
    int t = blockIdx.x * 256 + threadIdx.x;       // grid = 12800 blocks
    int i = t >> 3, part = t & 7;                 // i sequential -> coalesced reads
    int j = inv[i];
    const float4* p = (const float4*)(f + (long)i*64 + part*8);
    float4 a = p[0], b = p[1];
    union { uint4 q; __hip_bfloat16 h[8]; } u;
    u.h[0] = __float2bfloat16(a.x); u.h[1] = __float2bfloat16(a.y);
    u.h[2] = __float2bfloat16(a.z); u.h[3] = __float2bfloat16(a.w);
    u.h[4] = __float2bfloat16(b.x); u.h[5] = __float2bfloat16(b.y);
    u.h[6] = __float2bfloat16(b.z); u.h[7] = __float2bfloat16(b.w);
    *(uint4*)(fpermb + (long)j*64 + part*8) = u.q;
}

// neighbor table over SORTED order j; center tap (tt==4) omitted (always self).
// values are SORTED positions (index fpermb / y1 directly)
__global__ void nbr_kernel(const int* __restrict__ lsort, const int* __restrict__ grid,
                           int* __restrict__ nbrp) {
    int j = blockIdx.x * 256 + threadIdx.x;
    int lin = lsort[j];
    int b = lin / HW;
    int rem = lin - b*HW;
    int y = rem / WG;
    int x = rem - y*WG;
    int baseg = b*HW;
    #pragma unroll
    for (int tt = 0; tt < 9; ++tt) {
        if (tt == 4) continue;
        int ti = tt < 4 ? tt : tt - 1;
        int ny = y + tt/3 - 1, nx = x + tt%3 - 1;
        int g = -1;
        if (ny >= 0 && ny < HG && nx >= 0 && nx < WG)
            g = grid[baseg + ny*WG + nx];
        nbrp[ti*NP + j] = g;
    }
}

// weights pre-cast to bf16 in PER-LANE FRAGMENT order:
// flat index o = (((t*2+ks)*4 + c)*64 + lane)*8 + e
// holds w[t][k = ks*32 + (lane>>4)*8 + e][n = c*16 + (lane&15)]
// -> a wave's B-fragment load is ONE contiguous 1KB read (L1-resident, no LDS).
__global__ void cast_w_kernel(const float* __restrict__ w1, const float* __restrict__ w2,
                              const float* __restrict__ wd,
                              __hip_bfloat16* __restrict__ wc1, __hip_bfloat16* __restrict__ wc2) {
    int i = blockIdx.x * 256 + threadIdx.x;   // grid = 77824 threads exactly
    if (i < 9*4096) {
        int o = i;
        int e = o & 7, l = (o >> 3) & 63, c = (o >> 9) & 3, ks = (o >> 11) & 1, t = o >> 12;
        int n = c*16 + (l & 15), k = ks*32 + (l >> 4)*8 + e;
        wc1[o] = __float2bfloat16(w1[t*4096 + k*64 + n]);
    }
    int j = i - 9*4096;
    if (j >= 0 && j < 10*4096) {
        int o = j;
        int e = o & 7, l = (o >> 3) & 63, c = (o >> 9) & 3, ks = (o >> 11) & 1, t = o >> 12;
        int n = c*16 + (l & 15), k = ks*32 + (l >> 4)*8 + e;
        float v = (t < 9) ? w2[t*4096 + k*64 + n] : wd[k*64 + n];
        wc2[o] = __float2bfloat16(v);
    }
}

// ---------------- gather-GEMM conv kernel ----------------
// 128 sorted rows x 64 cols per block, 4 waves.
// A: double-buffered LDS, ONE barrier/tap. Staging is load->IMMEDIATE LDS write
// (r3 discipline: nothing held across the MFMA cluster except next tap's 1-int
// neighbor index -- the r2/r5 spills both came from held staging regs).
// B: read directly from global in per-lane fragment order (r5-verified), L1-hit.
// LDS ops per lane per tap: 4 writes + 4 reads (was 18 in r3).
// FINAL: residual tap computed POST-LOOP from global (r4-verified, no LDS,
// short-lived accR). Reference applies relu(conv2+b2) BEFORE adding residual.

#define LDA 72

template<bool FINAL>
__launch_bounds__(256)
__global__ void conv_kernel(const __hip_bfloat16* __restrict__ src,    // sorted-order gather source
                            const __hip_bfloat16* __restrict__ idsrc,  // identity source (FINAL)
                            const int* __restrict__ nbrp,              // [8][NP] sorted positions
                            const int* __restrict__ ord,               // sorted pos -> orig id
                            const __hip_bfloat16* __restrict__ wT,     // fragment-ordered weights
                            const float* __restrict__ bias,
                            __hip_bfloat16* __restrict__ out_bf,       // sorted order (conv1)
                            float* __restrict__ out_f) {               // original order (conv2)
    __shared__ __align__(16) __hip_bfloat16 As[2][128 * LDA];   // 2 x 18,432 B

    const int tid = threadIdx.x;
    // XCD-aware swizzle: 3200 blocks, 8 XCDs, 400 contiguous spatial tiles per XCD
    const int sbid = (blockIdx.x & 7) * 400 + (blockIdx.x >> 3);
    const int base = sbid * 128;
    const int wave = tid >> 6, lane = tid & 63;
    const int mrow = lane & 15, kq = lane >> 4;
    const int srow = tid >> 1, shalf = tid & 1;   // staging: 2 threads per row

    const bf16x8* wfrag = (const bf16x8*)wT;      // 16B per lane-fragment

    f32x4 acc[2][4];
    #pragma unroll
    for (int i = 0; i < 2; ++i)
        #pragma unroll
        for (int j = 0; j < 4; ++j)
            acc[i][j] = (f32x4){0.f, 0.f, 0.f, 0.f};

    auto gpos = [&](int t) -> int {
        if (t == 4) return base + srow;              // center tap = self
        int ti = t < 4 ? t : t - 1;
        return nbrp[ti*NP + base + srow];
    };

    // load -> IMMEDIATE LDS write (no regs survive past this call)
    auto stageA = [&](int g, int bsel) {
        uint4 v0, v1, v2, v3;
        if (g >= 0) {
            const uint4* p = (const uint4*)(src + (long)g*64 + shalf*32);
            v0 = p[0]; v1 = p[1]; v2 = p[2]; v3 = p[3];
        } else {
            v0 = v1 = v2 = v3 = make_uint4(0u, 0u, 0u, 0u);
        }
        uint4* dst = (uint4*)(As[bsel] + srow*LDA + shalf*32);
        dst[0] = v0; dst[1] = v1; dst[2] = v2; dst[3] = v3;
    };

    auto mfma_tap = [&](f32x4 (&ac)[2][4], int t, int cur) {
        #pragma unroll
        for (int ks = 0; ks < 2; ++ks) {
            int kb = ks*32 + kq*8;
            bf16x8 a0 = *(const bf16x8*)(&As[cur][(wave*32      + mrow)*LDA + kb]);
            bf16x8 a1 = *(const bf16x8*)(&As[cur][(wave*32 + 16 + mrow)*LDA + kb]);
            int fb = ((t*2 + ks)*4)*64 + lane;
            bf16x8 b0 = wfrag[fb];
            bf16x8 b1 = wfrag[fb + 64];
            bf16x8 b2 = wfrag[fb + 128];
            bf16x8 b3 = wfrag[fb + 192];
            ac[0][0] = __builtin_amdgcn_mfma_f32_16x16x32_bf16(a0, b0, ac[0][0], 0, 0, 0);
            ac[0][1] = __builtin_amdgcn_mfma_f32_16x16x32_bf16(a0, b1, ac[0][1], 0, 0, 0);
            ac[0][2] = __builtin_amdgcn_mfma_f32_16x16x32_bf16(a0, b2, ac[0][2], 0, 0, 0);
            ac[0][3] = __builtin_amdgcn_mfma_f32_16x16x32_bf16(a0, b3, ac[0][3], 0, 0, 0);
            ac[1][0] = __builtin_amdgcn_mfma_f32_16x16x32_bf16(a1, b0, ac[1][0], 0, 0, 0);
            ac[1][1] = __builtin_amdgcn_mfma_f32_16x16x32_bf16(a1, b1, ac[1][1], 0, 0, 0);
            ac[1][2] = __builtin_amdgcn_mfma_f32_16x16x32_bf16(a1, b2, ac[1][2], 0, 0, 0);
            ac[1][3] = __builtin_amdgcn_mfma_f32_16x16x32_bf16(a1, b3, ac[1][3], 0, 0, 0);
        }
    };

    // prologue: stage tap 0 into buf0; prefetch tap-1 index
    int g = gpos(0);
    stageA(g, 0);
    g = gpos(1);

    for (int t = 0; t < 9; ++t) {
        __syncthreads();   // buf[t&1] staged & visible; prior readers of buf[(t+1)&1] done
        if (t + 1 < 9) {
            stageA(g, (t + 1) & 1);   // write other buffer; current tap reads are unaffected
            if (t + 2 < 9) g = gpos(t + 2);
        }
        mfma_tap(acc, t, t & 1);
    }

    const int col = mrow, quad = kq;

    if (FINAL) {
        // residual tap: contiguous identity rows @ wd, straight from global (no LDS)
        f32x4 accR[2][4];
        #pragma unroll
        for (int i = 0; i < 2; ++i)
            #pragma unroll
            for (int j = 0; j < 4; ++j)
                accR[i][j] = (f32x4){0.f, 0.f, 0.f, 0.f};
        const int r0 = base + wave*32 + mrow, r1 = r0 + 16;
        #pragma unroll
        for (int ks = 0; ks < 2; ++ks) {
            int kb = ks*32 + kq*8;
            union { uint4 q; bf16x8 v; } ua0, ua1;
            ua0.q = *(const uint4*)(idsrc + (long)r0*64 + kb);
            ua1.q = *(const uint4*)(idsrc + (long)r1*64 + kb);
            int fb = ((9*2 + ks)*4)*64 + lane;
            bf16x8 b0 = wfrag[fb];
            bf16x8 b1 = wfrag[fb + 64];
            bf16x8 b2 = wfrag[fb + 128];
            bf16x8 b3 = wfrag[fb + 192];
            accR[0][0] = __builtin_amdgcn_mfma_f32_16x16x32_bf16(ua0.v, b0, accR[0][0], 0, 0, 0);
            accR[0][1] = __builtin_amdgcn_mfma_f32_16x16x32_bf16(ua0.v, b1, accR[0][1], 0, 0, 0);
            accR[0][2] = __builtin_amdgcn_mfma_f32_16x16x32_bf16(ua0.v, b2, accR[0][2], 0, 0, 0);
            accR[0][3] = __builtin_amdgcn_mfma_f32_16x16x32_bf16(ua0.v, b3, accR[0][3], 0, 0, 0);
            accR[1][0] = __builtin_amdgcn_mfma_f32_16x16x32_bf16(ua1.v, b0, accR[1][0], 0, 0, 0);
            accR[1][1] = __builtin_amdgcn_mfma_f32_16x16x32_bf16(ua1.v, b1, accR[1][1], 0, 0, 0);
            accR[1][2] = __builtin_amdgcn_mfma_f32_16x16x32_bf16(ua1.v, b2, accR[1][2], 0, 0, 0);
            accR[1][3] = __builtin_amdgcn_mfma_f32_16x16x32_bf16(ua1.v, b3, accR[1][3], 0, 0, 0);
        }
        #pragma unroll
        for (int cb = 0; cb < 4; ++cb) {
            float bv = bias[cb*16 + col];
            #pragma unroll
            for (int mb = 0; mb < 2; ++mb) {
                #pragma unroll
                for (int r = 0; r < 4; ++r) {
                    float v = acc[mb][cb][r] + bv;
                    v = v > 0.f ? v : 0.f;
                    v += accR[mb][cb][r];      // residual added AFTER inner relu
                    v = v > 0.f ? v : 0.f;
                    int srt = base + wave*32 + mb*16 + quad*4 + r;
                    long row = ord[srt];       // scatter to original order
                    out_f[row*64 + cb*16 + col] = v;
                }
            }
        }
    } else {
        #pragma unroll
        for (int cb = 0; cb < 4; ++cb) {
            float bv = bias[cb*16 + col];
            #pragma unroll
            for (int mb = 0; mb < 2; ++mb) {
                #pragma unroll
                for (int r = 0; r < 4; ++r) {
                    float v = acc[mb][cb][r] + bv;
                    v = v > 0.f ? v : 0.f;
                    int srt = base + wave*32 + mb*16 + quad*4 + r;
                    out_bf[(long)srt*64 + cb*16 + col] = __float2bfloat16(v);   // stay sorted
                }
            }
        }
    }
}

// ---------------- launch ----------------

extern "C" void kernel_launch(void* const* d_in, const int* in_sizes, int n_in,
                              void* d_out, int out_size, void* d_ws, size_t ws_size,
                              hipStream_t stream) {
    const float* features = (const float*)d_in[0];
    const int*   coords   = (const int*)d_in[1];
    const float* w1 = (const float*)d_in[2];
    const float* b1 = (const float*)d_in[3];
    const float* w2 = (const float*)d_in[4];
    const float* b2 = (const float*)d_in[5];
    const float* wd = (const float*)d_in[6];
    float* out = (float*)d_out;

    char* ws = (char*)d_ws;
    int*            grid   = (int*)ws;                           //  3,276,800 B
    int*            nbrp   = (int*)(ws + 3276800);               // 13,107,200 B (8 taps)
    int*            ord    = (int*)(ws + 16384000);              //  1,638,400 B
    __hip_bfloat16* fpermb = (__hip_bfloat16*)(ws + 18022400);   // 52,428,800 B
    __hip_bfloat16* y1     = (__hip_bfloat16*)(ws + 70451200);   // 52,428,800 B
    __hip_bfloat16* wc1    = (__hip_bfloat16*)(ws + 122880000);  //     73,728 B
    __hip_bfloat16* wc2    = (__hip_bfloat16*)(ws + 122953728);  //     81,920 B
    // total 123,035,648 B
    // lsort + hist + inv live in y1's region (dead before conv1 writes y1)
    int* lsort = (int*)(ws + 70451200);                          //  1,638,400 B
    int* hist  = (int*)(ws + 70451200 + 1638400);                //     12,800 B
    int* inv   = (int*)(ws + 70451200 + 1651200);                //  1,638,400 B

    hipMemsetAsync(hist, 0x00, (size_t)NTILE * sizeof(int), stream);

    hist_kernel     <<<1600,  256, 0, stream>>>(coords, hist, grid);   // also clears grid
    scan_kernel     <<<1,     256, 0, stream>>>(hist);
    ord_kernel      <<<1600,  256, 0, stream>>>(coords, hist, ord, lsort, grid, inv);
    cast_w_kernel   <<<304,   256, 0, stream>>>(w1, w2, wd, wc1, wc2);
    nbr_kernel      <<<1600,  256, 0, stream>>>(lsort, grid, nbrp);
    perm_cast_kernel<<<12800, 256, 0, stream>>>(features, inv, fpermb);

    conv_kernel<false><<<3200, 256, 0, stream>>>(fpermb, nullptr, nbrp, ord, wc1, b1, y1, nullptr);
    conv_kernel<true ><<<3200, 256, 0, stream>>>(y1, fpermb, nbrp, ord, wc2, b2, nullptr, out);
}